// Round 7
// baseline (31.718 us; speedup 1.0000x reference)
//
#include <hip/hip_runtime.h>
#include <hip/hip_fp16.h>

typedef _Float16 f16x8 __attribute__((ext_vector_type(8)));
typedef _Float16 f16x4 __attribute__((ext_vector_type(4)));
typedef float f32x4 __attribute__((ext_vector_type(4)));

namespace {
constexpr int K = 4096;
constexpr int N = 11008;
constexpr int NC = N / 8;      // packed int32 words per K-row = 1376
constexpr int M_ROWS = 32;
constexpr int KSPLIT = 8;      // K-slices of 512 (multiple of group size 128)
constexpr int BN = 128;        // output columns per block
constexpr int BK = 32;         // K rows per staging step
}

// out[m][n] = bias[n]  (fresh every call; GEMM kernel accumulates on top)
__global__ void init_out_kernel(const float* __restrict__ bias,
                                float* __restrict__ out) {
  const int n = blockIdx.x * 256 + threadIdx.x;
  out[blockIdx.y * N + n] = bias[n];
}

__global__ __launch_bounds__(256, 2) void awq_gemm_kernel(
    const int* __restrict__ qw, const int* __restrict__ qz,
    const float* __restrict__ sc, const float* __restrict__ x,
    float* __restrict__ out)
{
  // x tile: 32 rows x 32 halfs, padded to 40 (b128 frag reads: ≤2-way banks)
  __shared__ _Float16 lx[M_ROWS][40];
  // qweight tile: 32 k-rows x 16 words, padded to 17 (conflict-free b32 reads)
  __shared__ int lq[BK][17];

  const int tid  = threadIdx.x;
  const int lane = tid & 63;
  const int wid  = tid >> 6;      // wave 0..3
  const int kq   = lane >> 4;     // 0..3  (k-quarter within MFMA frag)
  const int c16  = lane & 15;     // fragment row/col index

  const int n0 = blockIdx.x * BN;
  const int c0 = n0 >> 3;

  // AWQ nibble shift for output column (n&7): 4 * AWQ_ORDER[n&7],
  // AWQ_ORDER=[0,4,1,5,2,6,3,7]  ->  sh = 4*((j>>1) + 4*(j&1))
  const int j7 = c16 & 7;
  const int sh = ((j7 >> 1) | ((j7 & 1) << 2)) << 2;

  int ncol[2], cglob[2], cloc[2];
#pragma unroll
  for (int t = 0; t < 2; ++t) {
    ncol[t]  = n0 + wid * 32 + t * 16 + c16;  // this lane's output column, n-tile t
    cglob[t] = ncol[t] >> 3;                  // packed word column (global)
    cloc[t]  = cglob[t] - c0;                 // packed word column within LDS tile
  }

  const int kbeg = blockIdx.y * (K / KSPLIT);
  const int kend = kbeg + (K / KSPLIT);

  f32x4 acc[2][2] = {};   // [m-tile][n-tile]
  float sf[2], zs[2];

  // staging: 8 threads per row (x: 16B f32 -> 8B f16; qw: 8B = 2 words)
  const int sr = tid >> 3;   // 0..31
  const int so = tid & 7;

  for (int k0 = kbeg; k0 < kend; k0 += BK) {
    if ((k0 & 127) == 0) {          // group boundary (kbeg is a multiple of 128)
      const int g = k0 >> 7;
#pragma unroll
      for (int t = 0; t < 2; ++t) {
        const int zq = qz[g * NC + cglob[t]];
        sf[t] = sc[g * N + ncol[t]];                       // f32 scale
        zs[t] = sf[t] * (float)((zq >> sh) & 15);
      }
    }

    // stage x[0:32][k0:k0+32] (f32 -> f16 on the fly; 16B load, 8B LDS write)
    {
      const float4 v = *reinterpret_cast<const float4*>(x + sr * K + k0 + so * 4);
      f16x4 h;
      h[0] = (_Float16)v.x; h[1] = (_Float16)v.y;
      h[2] = (_Float16)v.z; h[3] = (_Float16)v.w;
      *reinterpret_cast<f16x4*>(&lx[sr][so * 4]) = h;
    }
    // stage qweight[k0:k0+32][c0:c0+16]  (exactly one 64B line per row)
    {
      const int2 w = *reinterpret_cast<const int2*>(qw + (k0 + sr) * NC + c0 + so * 2);
      lq[sr][so * 2]     = w.x;
      lq[sr][so * 2 + 1] = w.y;
    }
    __syncthreads();

    // A fragments: row = lane&15 (+16 for second m-tile), k = kq*8 + j (contiguous)
    const f16x8 a0 = *reinterpret_cast<const f16x8*>(&lx[c16][kq * 8]);
    const f16x8 a1 = *reinterpret_cast<const f16x8*>(&lx[c16 + 16][kq * 8]);

#pragma unroll
    for (int t = 0; t < 2; ++t) {
      f16x8 b;   // B: col = lane&15, k = kq*8 + j
#pragma unroll
      for (int j = 0; j < 8; ++j) {
        const int q = lq[kq * 8 + j][cloc[t]];
        b[j] = (_Float16)fmaf((float)((q >> sh) & 15), sf[t], -zs[t]);  // (q-z)*s
      }
      acc[0][t] = __builtin_amdgcn_mfma_f32_16x16x32_f16(a0, b, acc[0][t], 0, 0, 0);
      acc[1][t] = __builtin_amdgcn_mfma_f32_16x16x32_f16(a1, b, acc[1][t], 0, 0, 0);
    }
    __syncthreads();
  }

  // C/D layout (m89-verified, dtype-independent): col = lane&15, row = (lane>>4)*4 + i
#pragma unroll
  for (int mt = 0; mt < 2; ++mt)
#pragma unroll
    for (int t = 0; t < 2; ++t)
#pragma unroll
      for (int i = 0; i < 4; ++i) {
        const int row = mt * 16 + kq * 4 + i;
        atomicAdd(out + row * N + ncol[t], acc[mt][t][i]);
      }
}

extern "C" void kernel_launch(void* const* d_in, const int* in_sizes, int n_in,
                              void* d_out, int out_size, void* d_ws, size_t ws_size,
                              hipStream_t stream) {
  const float* x    = (const float*)d_in[0];
  const int* qw     = (const int*)d_in[1];
  const int* qz     = (const int*)d_in[2];
  const float* sc   = (const float*)d_in[3];   // fp16 delivered as f32
  const float* bias = (const float*)d_in[4];   // fp16 delivered as f32
  float* out        = (float*)d_out;

  init_out_kernel<<<dim3(N / 256, M_ROWS), 256, 0, stream>>>(bias, out);
  awq_gemm_kernel<<<dim3(N / BN, KSPLIT), 256, 0, stream>>>(qw, qz, sc, x, out);
}